// Round 1
// baseline (603.384 us; speedup 1.0000x reference)
//
#include <hip/hip_runtime.h>
#include <math.h>

#define HD   64
#define EIN  8
#define SAS  168          // sW1 row stride in u16 (336 B): bank step 20 -> conflict-light
#define W2S  72           // sW2/X1 row stride in u16 (144 B)
#define NORM_INV 0.01f
#define NTH  256          // 4 waves/block
#define NBLK 1024         // 4 blocks/CU x 256 CUs (LDS: 4 x 40960 B = exactly 160 KiB)
#define NWAVES (NBLK * (NTH / 64))

typedef short bf16x8 __attribute__((ext_vector_type(8)));
typedef float f32x4  __attribute__((ext_vector_type(4)));
typedef float f4v    __attribute__((ext_vector_type(4)));

__device__ __forceinline__ unsigned short f2bf(float f) {
    union { float f; unsigned u; } v; v.f = f;
    unsigned r = v.u + 0x7FFFu + ((v.u >> 16) & 1u);
    return (unsigned short)(r >> 16);
}
__device__ __forceinline__ unsigned pk2(float a, float b) {
    return (unsigned)f2bf(a) | ((unsigned)f2bf(b) << 16);
}
__device__ __forceinline__ float silu_f(float x) {
    return x * __builtin_amdgcn_rcpf(1.0f + __expf(-x));
}

// prep: h -> bf16 table in ws + coord -> out copy
__global__ void prep_h_kernel(const float* __restrict__ h, unsigned short* __restrict__ hbf,
                              int npairs, const float* __restrict__ coord,
                              float* __restrict__ out, int n3) {
    int i = blockIdx.x * blockDim.x + threadIdx.x;
    if (i < npairs) {
        float2 v = reinterpret_cast<const float2*>(h)[i];
        ushort2 o; o.x = f2bf(v.x); o.y = f2bf(v.y);
        reinterpret_cast<ushort2*>(hbf)[i] = o;
    }
    if (i < n3) out[i] = coord[i];
}

__global__ void prep_out_kernel(const float* __restrict__ coord,
                                float* __restrict__ out, int n3) {
    int i = blockIdx.x * blockDim.x + threadIdx.x;
    if (i < n3) out[i] = coord[i];
}

// r6: latency-bound fix.
//  (a) 4 blocks/CU (launch_bounds min-waves 4, grid 1024) -- LDS fits exactly.
//  (b) 3-stage software pipeline: eidx loaded 2 iterations ahead, h/coord/eattr
//      gathers issued 1 iteration ahead, so the vmcnt wait for the fragments
//      consumed by this iteration's MFMAs lands after a full compute phase.
template <bool HB>
__global__ __launch_bounds__(NTH, 4) void egnn_mfma_kernel(
    const float* __restrict__ h,             // fp32 h (when !HB)
    const unsigned short* __restrict__ hbf,  // bf16 h table in ws (when HB)
    const float* __restrict__ coord,
    const int*   __restrict__ eidx,   // [2][E]
    const float* __restrict__ eattr,  // [E][8]
    const float* __restrict__ W1f,    // [136][64] fp32
    const float* __restrict__ W2f,    // [64][64] fp32
    const float* __restrict__ b1,
    const float* __restrict__ b2,
    const float* __restrict__ W3,
    float* __restrict__ out,
    int E_)
{
    __shared__ unsigned short sW1[64 * SAS];      // 21504 B
    __shared__ unsigned short sW2[64 * W2S];      //  9216 B
    __shared__ unsigned short sX1[64 * W2S];      //  9216 B (4 waves x 16 rows)
    __shared__ float sB1[64], sB2[64], sW3[64];   //   768 B

    const int t = threadIdx.x;

    // ---- weights -> LDS (once per block) ----
    for (int i = t; i < 136 * 64; i += NTH) {
        int k = i >> 6, n = i & 63;
        sW1[n * SAS + k] = f2bf(W1f[i]);
    }
    for (int i = t; i < 24 * 64; i += NTH) {      // zero-pad W1 k=136..159
        int n = i / 24, k = 136 + (i - n * 24);
        sW1[n * SAS + k] = 0;
    }
    for (int i = t; i < 64 * 64; i += NTH) {
        int k = i >> 6, n = i & 63;
        sW2[n * W2S + k] = f2bf(W2f[i]);
    }
    if (t < 64) sB1[t] = b1[t];
    else if (t < 128) sB2[t - 64] = b2[t - 64];
    else if (t < 192) sW3[t - 128] = W3[t - 128];
    __syncthreads();                               // the ONLY barrier

    const int w = t >> 6, lane = t & 63;
    const int m = lane & 15, q = lane >> 4;

    unsigned short* x1Row = sX1 + (16 * w + m) * W2S;  // this lane's edge row

    const int ngroups = (E_ + 15) >> 4;
    const int g0 = blockIdx.x * (NTH / 64) + w;

    // ---- pipeline stage registers ----
    int   e_c = 0, row_c = 0, col_c = 0;     // current group (data resident)
    float cr_c = 0.f, cc_c = 0.f;
    bf16x8 bf_c[5];
    int   e_n = 0, row_n = 0, col_n = 0;     // next group (indices resident)

    auto load_idx = [&](int g, int &e, int &row, int &col) {
        e = g * 16 + m;
        int ec = (e < E_) ? e : (E_ - 1);
        row = eidx[ec];
        col = eidx[(size_t)E_ + ec];
    };

    auto load_data = [&](int e, int row, int col,
                         float &cr, float &cc, bf16x8 *bf) {
        cr = 0.f; cc = 0.f;
        if (q < 3) { cr = coord[row * 3 + q]; cc = coord[col * 3 + q]; }
        if (HB) {
            const bf16x8* hr = (const bf16x8*)(hbf + (size_t)row * HD);
            const bf16x8* hc = (const bf16x8*)(hbf + (size_t)col * HD);
            bf[0] = hr[q];          // k =   q*8 .. +8
            bf[1] = hr[4 + q];      // k = 32+q*8
            bf[2] = hc[q];          // k = 64+...
            bf[3] = hc[4 + q];      // k = 96+...
        } else {
            const f4v* hr = (const f4v*)(h + (size_t)row * HD);
            const f4v* hc = (const f4v*)(h + (size_t)col * HD);
#pragma unroll
            for (int s = 0; s < 4; ++s) {
                const f4v* src = (s < 2) ? hr : hc;
                f4v a = src[(s & 1) * 8 + q * 2];
                f4v b = src[(s & 1) * 8 + q * 2 + 1];
                union { bf16x8 v; uint4 u; } pk;
                pk.u.x = pk2(a.x, a.y); pk.u.y = pk2(a.z, a.w);
                pk.u.z = pk2(b.x, b.y); pk.u.w = pk2(b.z, b.w);
                bf[s] = pk.v;
            }
        }
        int ec = (e < E_) ? e : (E_ - 1);
        union { bf16x8 v; uint4 u; } pk;
        pk.u.x = 0; pk.u.y = 0; pk.u.z = 0; pk.u.w = 0;
        if (q == 0) {                       // k = 128..135: edge_attr
            f4v a0 = ((const f4v*)(eattr + (size_t)ec * EIN))[0];
            f4v a1 = ((const f4v*)(eattr + (size_t)ec * EIN))[1];
            pk.u.x = pk2(a0.x, a0.y); pk.u.y = pk2(a0.z, a0.w);
            pk.u.z = pk2(a1.x, a1.y); pk.u.w = pk2(a1.z, a1.w);
        }
        bf[4] = pk.v;                       // q>0: zeros (W1 pad also zero)
    };

    // ---- prologue: fill the pipeline ----
    if (g0 < ngroups) {
        load_idx(g0, e_c, row_c, col_c);
        load_data(e_c, row_c, col_c, cr_c, cc_c, bf_c);
        if (g0 + NWAVES < ngroups)
            load_idx(g0 + NWAVES, e_n, row_n, col_n);
    }

    for (int g = g0; g < ngroups; g += NWAVES) {
        const int gn = g + NWAVES;

        // -------- prefetch: issue next group's gathers BEFORE compute --------
        float cr_n = 0.f, cc_n = 0.f;
        bf16x8 bf_n[5];
        if (gn < ngroups)
            load_data(e_n, row_n, col_n, cr_n, cc_n, bf_n);
        int e_n2 = 0, row_n2 = 0, col_n2 = 0;
        if (gn + NWAVES < ngroups)
            load_idx(gn + NWAVES, e_n2, row_n2, col_n2);

        // ---------- layer 1: D1[n2][e] = sum_k W1[n2][k] * inp[e][k] ----------
        f32x4 acc1[4] = {};
#pragma unroll
        for (int s = 0; s < 5; ++s) {
#pragma unroll
            for (int nt = 0; nt < 4; ++nt) {
                bf16x8 afrag = *(const bf16x8*)(sW1 + (16 * nt + m) * SAS + s * 32 + q * 8);
                acc1[nt] = __builtin_amdgcn_mfma_f32_16x16x32_bf16(afrag, bf_c[s], acc1[nt], 0, 0, 0);
            }
        }

        // silu(+b1) -> X1[e][k] packed b64 per lane
#pragma unroll
        for (int nt = 0; nt < 4; ++nt) {
            float4 bb = *(const float4*)(&sB1[16 * nt + 4 * q]);
            ushort4 o;
            o.x = f2bf(silu_f(acc1[nt][0] + bb.x));
            o.y = f2bf(silu_f(acc1[nt][1] + bb.y));
            o.z = f2bf(silu_f(acc1[nt][2] + bb.z));
            o.w = f2bf(silu_f(acc1[nt][3] + bb.w));
            *((ushort4*)(x1Row + 16 * nt + 4 * q)) = o;
        }

        // ---------- layer 2: D2[n2][e] = sum_k W2[n2][k] * X1[e][k] ----------
        f32x4 acc2[4] = {};
#pragma unroll
        for (int s = 0; s < 2; ++s) {
            bf16x8 bfrag = *(const bf16x8*)(x1Row + s * 32 + q * 8);
#pragma unroll
            for (int nt = 0; nt < 4; ++nt) {
                bf16x8 afrag = *(const bf16x8*)(sW2 + (16 * nt + m) * W2S + s * 32 + q * 8);
                acc2[nt] = __builtin_amdgcn_mfma_f32_16x16x32_bf16(afrag, bfrag, acc2[nt], 0, 0, 0);
            }
        }

        // ---------- epilogue: scal = silu(X2) . W3, all in registers ----------
        float p = 0.f;
#pragma unroll
        for (int nt = 0; nt < 4; ++nt) {
            float4 b2v = *(const float4*)(&sB2[16 * nt + 4 * q]);
            float4 w3v = *(const float4*)(&sW3[16 * nt + 4 * q]);
            p = fmaf(silu_f(acc2[nt][0] + b2v.x), w3v.x, p);
            p = fmaf(silu_f(acc2[nt][1] + b2v.y), w3v.y, p);
            p = fmaf(silu_f(acc2[nt][2] + b2v.z), w3v.z, p);
            p = fmaf(silu_f(acc2[nt][3] + b2v.w), w3v.w, p);
        }
        p += __shfl_xor(p, 16);
        p += __shfl_xor(p, 32);

        // distributed coord-diff: lane (q,m) owns component q of edge m
        float cd = cr_c - cc_c;                    // q==3 lanes contribute 0
        float r2 = cd * cd;
        r2 += __shfl_xor(r2, 16);
        r2 += __shfl_xor(r2, 32);
        if (e_c < E_ && q < 3) {
            float inv = __builtin_amdgcn_rcpf(sqrtf(r2 + 1e-8f) + 1.0f);
            atomicAdd(&out[row_c * 3 + q], cd * (p * NORM_INV * inv));
        }

        // -------- rotate pipeline --------
        e_c = e_n; row_c = row_n; col_c = col_n;
        cr_c = cr_n; cc_c = cc_n;
        bf_c[0] = bf_n[0]; bf_c[1] = bf_n[1]; bf_c[2] = bf_n[2];
        bf_c[3] = bf_n[3]; bf_c[4] = bf_n[4];
        e_n = e_n2; row_n = row_n2; col_n = col_n2;
    }
}

extern "C" void kernel_launch(void* const* d_in, const int* in_sizes, int n_in,
                              void* d_out, int out_size, void* d_ws, size_t ws_size,
                              hipStream_t stream) {
    const float* h         = (const float*)d_in[0];
    const float* coord     = (const float*)d_in[1];
    const int*   eidx      = (const int*)  d_in[2];
    const float* edge_attr = (const float*)d_in[3];
    const float* W1        = (const float*)d_in[4];
    const float* b1        = (const float*)d_in[5];
    const float* W2        = (const float*)d_in[6];
    const float* b2        = (const float*)d_in[7];
    const float* W3        = (const float*)d_in[8];
    float* out = (float*)d_out;

    int E_ = in_sizes[2] / 2;    // edge_index is [2, E]
    int n3 = out_size;           // N*3
    int nf = in_sizes[0];        // N*HD floats of h

    if (ws_size >= (size_t)nf * 2) {             // bf16 h table (6.4 MB)
        unsigned short* hbf = (unsigned short*)d_ws;
        int npairs = nf / 2;
        int pgrid = (npairs > n3 ? npairs : n3);
        hipLaunchKernelGGL(prep_h_kernel, dim3((pgrid + 255) / 256), dim3(256), 0, stream,
                           h, hbf, npairs, coord, out, n3);
        hipLaunchKernelGGL((egnn_mfma_kernel<true>), dim3(NBLK), dim3(NTH), 0, stream,
                           h, hbf, coord, eidx, edge_attr, W1, W2, b1, b2, W3, out, E_);
    } else {
        hipLaunchKernelGGL(prep_out_kernel, dim3((n3 + 255) / 256), dim3(256), 0, stream,
                           coord, out, n3);
        hipLaunchKernelGGL((egnn_mfma_kernel<false>), dim3(NBLK), dim3(NTH), 0, stream,
                           h, (const unsigned short*)nullptr, coord, eidx, edge_attr,
                           W1, W2, b1, b2, W3, out, E_);
    }
}